// Round 8
// baseline (478.358 us; speedup 1.0000x reference)
//
#include <hip/hip_runtime.h>

// ---------- problem constants ----------
#define HH 96
#define WW 96
#define NPIX (HH*WW)        // 9216
#define CC 64
#define CH 32               // C/2
#define BB 2
#define NKV 144             // NPIX / 64
#define NSPLIT 6
#define KPT (NKV/NSPLIT)    // 24 KV tiles per split

typedef short bh8 __attribute__((ext_vector_type(8)));
typedef float f32x4 __attribute__((ext_vector_type(4)));
typedef uint2 __attribute__((may_alias)) u2ma;
typedef float4 __attribute__((may_alias)) f4ma;

union FragU { bh8 v; uint2 q[2]; unsigned int w[4]; unsigned short u[8]; };

static __device__ __forceinline__ unsigned short f2b(float f){
    union { float f; unsigned int i; } v; v.f = f;
    unsigned int x = v.i;
    unsigned int r = (x + 0x7fffu + ((x >> 16) & 1u)) >> 16;   // RNE, finite values only
    return (unsigned short)r;
}
static __device__ __forceinline__ unsigned int pk_bf16(float lo, float hi){
    unsigned int r;
    asm("v_cvt_pk_bf16_f32 %0, %1, %2" : "=v"(r) : "v"(lo), "v"(hi));
    return r;
}
static __device__ __forceinline__ float hmax4(f32x4 v){
    return fmaxf(fmaxf(v[0], v[1]), fmaxf(v[2], v[3]));
}
static __device__ __forceinline__ float hadd4(f32x4 v){
    return (v[0] + v[1]) + (v[2] + v[3]);
}

// ---------- kernel 1: conv3x3 + bias + PReLU for both modalities ----------
// grid (6,6,16): z = ((mod*2 + b)*4 + cq), block 256 = 16x16 pixels
__global__ __launch_bounds__(256) void k_trunk1(
    const float* __restrict__ rgb, const float* __restrict__ dep,
    const float* __restrict__ w1, const float* __restrict__ b1,
    const float* __restrict__ a1p, float* __restrict__ t)
{
    __shared__ float xt[16][18][20];   // 23 KB
    int z   = blockIdx.z;
    int cq  = z & 3;
    int mb  = z >> 2;
    int b   = mb & 1;
    int mod = mb >> 1;
    int tx = threadIdx.x & 15, ty = threadIdx.x >> 4;
    int h0 = blockIdx.y * 16, w0 = blockIdx.x * 16;
    const float* x = (mod ? dep : rgb) + (size_t)b * CC * NPIX;
    float a1 = a1p[0];

    float acc[16];
    #pragma unroll
    for (int i = 0; i < 16; ++i) acc[i] = b1[cq*16 + i];

    for (int cc0 = 0; cc0 < CC; cc0 += 16){
        __syncthreads();
        for (int idx = threadIdx.x; idx < 16*18*18; idx += 256){
            int ci = idx / 324;
            int rem = idx - ci * 324;
            int r = rem / 18, c = rem - r * 18;
            int gh = h0 + r - 1, gw = w0 + c - 1;
            float v = 0.f;
            if (gh >= 0 && gh < HH && gw >= 0 && gw < WW)
                v = x[(cc0 + ci) * NPIX + gh * WW + gw];
            xt[ci][r][c] = v;
        }
        __syncthreads();
        for (int ci = 0; ci < 16; ++ci){
            float nb[9];
            #pragma unroll
            for (int dy = 0; dy < 3; ++dy)
                #pragma unroll
                for (int dx = 0; dx < 3; ++dx)
                    nb[dy*3+dx] = xt[ci][ty+dy][tx+dx];
            // w1 flat [co][ci][3][3]; uniform pointer -> scalar loads
            const float* wp = w1 + (size_t)cq * 16 * 576 + (cc0 + ci) * 9;
            #pragma unroll
            for (int co = 0; co < 16; ++co){
                float s = 0.f;
                #pragma unroll
                for (int k = 0; k < 9; ++k) s = fmaf(nb[k], wp[co*576 + k], s);
                acc[co] += s;
            }
        }
    }
    size_t tb = (size_t)(mod*2 + b) * CC * NPIX;
    int pix = (h0 + ty) * WW + (w0 + tx);
    #pragma unroll
    for (int i = 0; i < 16; ++i){
        float v = acc[i];
        v = (v >= 0.f) ? v : a1 * v;
        t[tb + (size_t)(cq*16 + i) * NPIX + pix] = v;
    }
}

// ---------- kernel 2: conv1x1+PReLU trunks + 3 projections ----------
// block 256 = 64 pixels x 4 cout-groups; grid 288
__global__ __launch_bounds__(256) void k_trunk2(
    const float* __restrict__ t,
    const float* __restrict__ w2, const float* __restrict__ b2,
    const float* __restrict__ a2p,
    const float* __restrict__ wch1, const float* __restrict__ wch2,
    const float* __restrict__ wch3,
    float* __restrict__ d0, unsigned short* __restrict__ c1t,
    unsigned short* __restrict__ d1, unsigned short* __restrict__ d2t)
{
    __shared__ float w2s[64][64];                            // [co][ci]
    __shared__ float wc1[32][64], wc2[32][64], wc3[32][64];  // [co2][ci]
    __shared__ float b2s[64];
    __shared__ float c0buf[64][65];                          // [pixel][ci], padded

    int tid = threadIdx.x;
    for (int i = tid; i < 4096; i += 256) w2s[i >> 6][i & 63] = w2[i];
    for (int i = tid; i < 2048; i += 256){
        int co2 = i >> 6, ci = i & 63;
        wc1[co2][ci] = wch1[i];
        wc2[co2][ci] = wch2[i];
        wc3[co2][ci] = wch3[i];
    }
    if (tid < 64) b2s[tid] = b2[tid];
    float a2 = a2p[0];
    __syncthreads();

    int pl = tid & 63, grp = tid >> 6;
    int P = blockIdx.x * 64 + pl;
    int b = P / NPIX, p = P % NPIX;

    for (int mod = 0; mod < 2; ++mod){
        const float* tp = t + (size_t)(mod*2 + b) * CC * NPIX + p;
        float acc[16];
        #pragma unroll
        for (int i = 0; i < 16; ++i) acc[i] = 0.f;
        for (int ci = 0; ci < 64; ++ci){
            float x = tp[ci * NPIX];
            #pragma unroll
            for (int i = 0; i < 16; ++i) acc[i] = fmaf(x, w2s[grp*16 + i][ci], acc[i]);
        }
        float c0v[16];
        #pragma unroll
        for (int i = 0; i < 16; ++i){
            float v = acc[i] + b2s[grp*16 + i];
            c0v[i] = (v >= 0.f) ? v : a2 * v;
        }
        __syncthreads();                       // protect c0buf from previous pass readers
        #pragma unroll
        for (int i = 0; i < 16; ++i) c0buf[pl][grp*16 + i] = c0v[i];
        __syncthreads();

        if (mod == 0){
            float ca[8];
            #pragma unroll
            for (int j = 0; j < 8; ++j) ca[j] = 0.f;
            for (int ci = 0; ci < 64; ++ci){
                float xc = c0buf[pl][ci];
                #pragma unroll
                for (int j = 0; j < 8; ++j) ca[j] = fmaf(xc, wc1[grp*8 + j][ci], ca[j]);
            }
            #pragma unroll
            for (int j = 0; j < 8; ++j)
                c1t[((size_t)b * CH + grp*8 + j) * NPIX + p] = f2b(ca[j]);
        } else {
            #pragma unroll
            for (int i = 0; i < 16; ++i)
                d0[((size_t)b * CC + grp*16 + i) * NPIX + p] = c0v[i];
            float ca[8], cb[8];
            #pragma unroll
            for (int j = 0; j < 8; ++j){ ca[j] = 0.f; cb[j] = 0.f; }
            for (int ci = 0; ci < 64; ++ci){
                float xc = c0buf[pl][ci];
                #pragma unroll
                for (int j = 0; j < 8; ++j){
                    ca[j] = fmaf(xc, wc2[grp*8 + j][ci], ca[j]);
                    cb[j] = fmaf(xc, wc3[grp*8 + j][ci], cb[j]);
                }
            }
            #pragma unroll
            for (int j = 0; j < 8; ++j){
                d1 [((size_t)b * NPIX + p) * CH + grp*8 + j] = f2b(ca[j]);
                d2t[((size_t)b * NPIX + p) * CH + grp*8 + j] = f2b(cb[j]);
            }
        }
    }
}

// ---------- attention helpers: explicit register double-buffer pipeline ------
static __device__ __forceinline__ void load_tile(
    const unsigned short* __restrict__ d2b, const unsigned short* __restrict__ c1b,
    int kb, int l16, int lg, FragU kf[4], FragU vf[4])
{
    #pragma unroll
    for (int j = 0; j < 4; ++j){
        const unsigned short* kp = d2b + (size_t)(kb + j*16 + l16) * CH + lg * 4;
        kf[j].q[0] = *(const u2ma*)kp;
        kf[j].q[1] = *(const u2ma*)(kp + 16);
    }
    #pragma unroll
    for (int w = 0; w < 2; ++w)
        #pragma unroll
        for (int jt = 0; jt < 2; ++jt){
            const unsigned short* vp = c1b + (size_t)(jt*16 + l16) * NPIX + kb + w*32 + lg*4;
            vf[w*2 + jt].q[0] = *(const u2ma*)vp;
            vf[w*2 + jt].q[1] = *(const u2ma*)(vp + 16);
        }
}

static __device__ __forceinline__ void compute_tile(
    const FragU& qf, FragU kf[4], FragU vf[4],
    f32x4& o0, f32x4& o1, float& m, float& lsum)
{
    // S^T tile j: rows k = kb+j*16+lg*4+i, col q = l16
    f32x4 s[4];
    #pragma unroll
    for (int j = 0; j < 4; ++j){
        f32x4 z = {0.f,0.f,0.f,0.f};
        s[j] = __builtin_amdgcn_mfma_f32_16x16x32_bf16(kf[j].v, qf.v, z, 0, 0, 0);
    }
    // online softmax over this lane's q-column
    float pm = fmaxf(fmaxf(hmax4(s[0]), hmax4(s[1])),
                     fmaxf(hmax4(s[2]), hmax4(s[3])));
    pm = fmaxf(pm, __shfl_xor(pm, 16));
    pm = fmaxf(pm, __shfl_xor(pm, 32));
    float mn = fmaxf(m, pm);
    float al = __expf(m - mn);
    m = mn;
    #pragma unroll
    for (int j = 0; j < 4; ++j)
        #pragma unroll
        for (int i = 0; i < 4; ++i)
            s[j][i] = __expf(s[j][i] - m);     // exp in place (saves 16 VGPR)
    float ps = (hadd4(s[0]) + hadd4(s[1])) + (hadd4(s[2]) + hadd4(s[3]));
    ps += __shfl_xor(ps, 16);
    ps += __shfl_xor(ps, 32);
    lsum = lsum * al + ps;
    o0 *= al;
    o1 *= al;
    // pack P^T B-frags in-register
    FragU p0, p1;
    p0.w[0] = pk_bf16(s[0][0], s[0][1]);
    p0.w[1] = pk_bf16(s[0][2], s[0][3]);
    p0.w[2] = pk_bf16(s[1][0], s[1][1]);
    p0.w[3] = pk_bf16(s[1][2], s[1][3]);
    p1.w[0] = pk_bf16(s[2][0], s[2][1]);
    p1.w[1] = pk_bf16(s[2][2], s[2][3]);
    p1.w[2] = pk_bf16(s[3][0], s[3][1]);
    p1.w[3] = pk_bf16(s[3][2], s[3][3]);
    // O^T += V^T P^T
    o0 = __builtin_amdgcn_mfma_f32_16x16x32_bf16(vf[0].v, p0.v, o0, 0, 0, 0);
    o1 = __builtin_amdgcn_mfma_f32_16x16x32_bf16(vf[1].v, p0.v, o1, 0, 0, 0);
    o0 = __builtin_amdgcn_mfma_f32_16x16x32_bf16(vf[2].v, p1.v, o0, 0, 0, 0);
    o1 = __builtin_amdgcn_mfma_f32_16x16x32_bf16(vf[3].v, p1.v, o1, 0, 0, 0);
}

// ---------- kernel 3: flash attention, K-split, reg-pipelined ---------------
// grid (144, B, NSPLIT); block 256 = 4 waves; wave = 16 query rows; KBLK = 64
// __launch_bounds__(256, 4): cap occupancy at 4 waves/SIMD -> 128-VGPR budget
// so the A/B register double-buffer (16 frags in flight) can materialize.
__global__ __launch_bounds__(256, 4) void k_attn(
    const unsigned short* __restrict__ d1, const unsigned short* __restrict__ d2t,
    const unsigned short* __restrict__ c1t, float* __restrict__ Opart,
    float* __restrict__ mpart, float* __restrict__ lpart)
{
    int b    = blockIdx.y;
    int sp   = blockIdx.z;
    int wid  = threadIdx.x >> 6;
    int lane = threadIdx.x & 63;
    int l16  = lane & 15;
    int lg   = lane >> 4;                 // 0..3
    int q0   = (blockIdx.x * 4 + wid) * 16;

    const unsigned short* d2b = d2t + (size_t)b * NPIX * CH;
    const unsigned short* c1b = c1t + (size_t)b * CH * NPIX;

    FragU qf;   // B-frag of Q^T == per-lane rows of Q
    {
        const unsigned short* qp = d1 + ((size_t)b * NPIX + q0 + l16) * CH + lg * 4;
        qf.q[0] = *(const u2ma*)qp;
        qf.q[1] = *(const u2ma*)(qp + 16);
    }

    f32x4 o0 = {0.f,0.f,0.f,0.f}, o1 = {0.f,0.f,0.f,0.f};   // O^T d-tiles 0,1
    float m = -1e30f, lsum = 0.f;

    FragU kA[4], vA[4], kB[4], vB[4];
    int t0 = sp * KPT;
    load_tile(d2b, c1b, t0 * 64, l16, lg, kA, vA);
    __builtin_amdgcn_sched_barrier(0);     // loads stay issued before compute

    #pragma unroll 1
    for (int i = 0; i < KPT; i += 2){
        load_tile(d2b, c1b, (t0 + i + 1) * 64, l16, lg, kB, vB);
        __builtin_amdgcn_sched_barrier(0);
        compute_tile(qf, kA, vA, o0, o1, m, lsum);
        int i2 = (i + 2 < KPT) ? i + 2 : KPT - 1;   // clamp: last prefetch redundant
        load_tile(d2b, c1b, (t0 + i2) * 64, l16, lg, kA, vA);
        __builtin_amdgcn_sched_barrier(0);
        compute_tile(qf, kB, vB, o0, o1, m, lsum);
    }

    // --- write unnormalized partials: lane holds q = q0+l16, d = jt*16+lg*4+i ---
    size_t prow = (size_t)(sp * BB + b) * NPIX + q0 + l16;
    float4 st0 = {o0[0], o0[1], o0[2], o0[3]};
    float4 st1 = {o1[0], o1[1], o1[2], o1[3]};
    *(f4ma*)(Opart + prow * CH + lg*4)      = st0;
    *(f4ma*)(Opart + prow * CH + 16 + lg*4) = st1;
    if (lg == 0){
        mpart[prow] = m;
        lpart[prow] = lsum;
    }
}

// ---------- kernel 4: combine K-split partials + 1x1 conv (32->64) + residual --
// block 256 = 64 pixels x 4 cout-groups; grid 288
__global__ __launch_bounds__(256) void k_final(
    const float* __restrict__ Opart, const float* __restrict__ mpart,
    const float* __restrict__ lpart, const float* __restrict__ wch4,
    const float* __restrict__ d0, float* __restrict__ out)
{
    __shared__ float w4s[64][32];   // [co][d]
    __shared__ float ob[64][33];    // combined O per pixel, padded
    int tid = threadIdx.x;
    for (int i = tid; i < 2048; i += 256) w4s[i >> 5][i & 31] = wch4[i];
    int pl = tid & 63, grp = tid >> 6;
    int P = blockIdx.x * 64 + pl;
    int b = P / NPIX, p = P % NPIX;

    // combine: thread (pl,grp) merges d = grp*8 .. grp*8+7
    float mv[NSPLIT];
    float M = -1e30f;
    #pragma unroll
    for (int s = 0; s < NSPLIT; ++s){
        mv[s] = mpart[(size_t)(s * BB + b) * NPIX + p];
        M = fmaxf(M, mv[s]);
    }
    float L = 0.f, acc8[8];
    #pragma unroll
    for (int j = 0; j < 8; ++j) acc8[j] = 0.f;
    #pragma unroll
    for (int s = 0; s < NSPLIT; ++s){
        float w = __expf(mv[s] - M);
        L += w * lpart[(size_t)(s * BB + b) * NPIX + p];
        const float* op = Opart + ((size_t)(s * BB + b) * NPIX + p) * CH + grp*8;
        #pragma unroll
        for (int j = 0; j < 8; ++j) acc8[j] = fmaf(w, op[j], acc8[j]);
    }
    float invL = 1.f / L;
    #pragma unroll
    for (int j = 0; j < 8; ++j) ob[pl][grp*8 + j] = acc8[j] * invL;
    __syncthreads();

    float acc[16];
    #pragma unroll
    for (int i = 0; i < 16; ++i) acc[i] = 0.f;
    #pragma unroll
    for (int d = 0; d < 32; ++d){
        float x = ob[pl][d];
        #pragma unroll
        for (int i = 0; i < 16; ++i) acc[i] = fmaf(x, w4s[grp*16 + i][d], acc[i]);
    }
    #pragma unroll
    for (int i = 0; i < 16; ++i){
        size_t idx = ((size_t)b * CC + grp*16 + i) * NPIX + p;
        out[idx] = acc[i] + d0[idx];
    }
}

// ---------- launch ----------
extern "C" void kernel_launch(void* const* d_in, const int* in_sizes, int n_in,
                              void* d_out, int out_size, void* d_ws, size_t ws_size,
                              hipStream_t stream) {
    const float* rgb  = (const float*)d_in[0];
    const float* dep  = (const float*)d_in[1];
    const float* w1   = (const float*)d_in[2];
    const float* b1   = (const float*)d_in[3];
    const float* a1   = (const float*)d_in[4];
    const float* w2   = (const float*)d_in[5];
    const float* b2   = (const float*)d_in[6];
    const float* a2   = (const float*)d_in[7];
    const float* wch1 = (const float*)d_in[8];
    const float* wch2 = (const float*)d_in[9];
    const float* wch3 = (const float*)d_in[10];
    const float* wch4 = (const float*)d_in[11];

    char* ws = (char*)d_ws;
    float* t             = (float*)(ws);                          //  9,437,184 B
    float* d0            = (float*)(ws + 9437184);                //  4,718,592 B
    unsigned short* c1t  = (unsigned short*)(ws + 14155776);      //  1,179,648 B
    unsigned short* d1   = (unsigned short*)(ws + 15335424);      //  1,179,648 B
    unsigned short* d2t  = (unsigned short*)(ws + 16515072);      //  1,179,648 B
    float* Opart         = (float*)(ws + 17694720);               // 14,155,776 B
    float* mpart         = (float*)(ws + 31850496);               //    442,368 B
    float* lpart         = (float*)(ws + 32292864);               //    442,368 B
    // total ws use: 32,735,232 B

    k_trunk1<<<dim3(6,6,16), 256, 0, stream>>>(rgb, dep, w1, b1, a1, t);
    k_trunk2<<<288, 256, 0, stream>>>(t, w2, b2, a2, wch1, wch2, wch3, d0, c1t, d1, d2t);
    k_attn  <<<dim3(NKV, BB, NSPLIT), 256, 0, stream>>>(d1, d2t, c1t, Opart, mpart, lpart);
    k_final <<<288, 256, 0, stream>>>(Opart, mpart, lpart, wch4, d0, (float*)d_out);
}

// Round 9
// 326.052 us; speedup vs baseline: 1.4671x; 1.4671x over previous
//
#include <hip/hip_runtime.h>

// ---------- problem constants ----------
#define HH 96
#define WW 96
#define NPIX (HH*WW)        // 9216
#define CC 64
#define CH 32               // C/2
#define BB 2
#define NKV 144             // NPIX / 64
#define NSPLIT 6
#define KPT (NKV/NSPLIT)    // 24 KV tiles per split

typedef short bh8 __attribute__((ext_vector_type(8)));
typedef float f32x4 __attribute__((ext_vector_type(4)));
typedef uint2 __attribute__((may_alias)) u2ma;
typedef float4 __attribute__((may_alias)) f4ma;

union FragU { bh8 v; uint2 q[2]; unsigned int w[4]; unsigned short u[8]; };

static __device__ __forceinline__ unsigned short f2b(float f){
    union { float f; unsigned int i; } v; v.f = f;
    unsigned int x = v.i;
    unsigned int r = (x + 0x7fffu + ((x >> 16) & 1u)) >> 16;   // RNE, finite values only
    return (unsigned short)r;
}
static __device__ __forceinline__ unsigned int pk_bf16(float lo, float hi){
    unsigned int r;
    asm("v_cvt_pk_bf16_f32 %0, %1, %2" : "=v"(r) : "v"(lo), "v"(hi));
    return r;
}
static __device__ __forceinline__ float hmax4(f32x4 v){
    return fmaxf(fmaxf(v[0], v[1]), fmaxf(v[2], v[3]));
}
static __device__ __forceinline__ float hadd4(f32x4 v){
    return (v[0] + v[1]) + (v[2] + v[3]);
}

// ---------- kernel 1: conv3x3 + bias + PReLU for both modalities ----------
// grid (6,6,16): z = ((mod*2 + b)*4 + cq), block 256 = 16x16 pixels
__global__ __launch_bounds__(256) void k_trunk1(
    const float* __restrict__ rgb, const float* __restrict__ dep,
    const float* __restrict__ w1, const float* __restrict__ b1,
    const float* __restrict__ a1p, float* __restrict__ t)
{
    __shared__ float xt[16][18][20];   // 23 KB
    int z   = blockIdx.z;
    int cq  = z & 3;
    int mb  = z >> 2;
    int b   = mb & 1;
    int mod = mb >> 1;
    int tx = threadIdx.x & 15, ty = threadIdx.x >> 4;
    int h0 = blockIdx.y * 16, w0 = blockIdx.x * 16;
    const float* x = (mod ? dep : rgb) + (size_t)b * CC * NPIX;
    float a1 = a1p[0];

    float acc[16];
    #pragma unroll
    for (int i = 0; i < 16; ++i) acc[i] = b1[cq*16 + i];

    for (int cc0 = 0; cc0 < CC; cc0 += 16){
        __syncthreads();
        for (int idx = threadIdx.x; idx < 16*18*18; idx += 256){
            int ci = idx / 324;
            int rem = idx - ci * 324;
            int r = rem / 18, c = rem - r * 18;
            int gh = h0 + r - 1, gw = w0 + c - 1;
            float v = 0.f;
            if (gh >= 0 && gh < HH && gw >= 0 && gw < WW)
                v = x[(cc0 + ci) * NPIX + gh * WW + gw];
            xt[ci][r][c] = v;
        }
        __syncthreads();
        for (int ci = 0; ci < 16; ++ci){
            float nb[9];
            #pragma unroll
            for (int dy = 0; dy < 3; ++dy)
                #pragma unroll
                for (int dx = 0; dx < 3; ++dx)
                    nb[dy*3+dx] = xt[ci][ty+dy][tx+dx];
            // w1 flat [co][ci][3][3]; uniform pointer -> scalar loads
            const float* wp = w1 + (size_t)cq * 16 * 576 + (cc0 + ci) * 9;
            #pragma unroll
            for (int co = 0; co < 16; ++co){
                float s = 0.f;
                #pragma unroll
                for (int k = 0; k < 9; ++k) s = fmaf(nb[k], wp[co*576 + k], s);
                acc[co] += s;
            }
        }
    }
    size_t tb = (size_t)(mod*2 + b) * CC * NPIX;
    int pix = (h0 + ty) * WW + (w0 + tx);
    #pragma unroll
    for (int i = 0; i < 16; ++i){
        float v = acc[i];
        v = (v >= 0.f) ? v : a1 * v;
        t[tb + (size_t)(cq*16 + i) * NPIX + pix] = v;
    }
}

// ---------- kernel 2: conv1x1+PReLU trunks + 3 projections ----------
// block 256 = 64 pixels x 4 cout-groups; grid 288
__global__ __launch_bounds__(256) void k_trunk2(
    const float* __restrict__ t,
    const float* __restrict__ w2, const float* __restrict__ b2,
    const float* __restrict__ a2p,
    const float* __restrict__ wch1, const float* __restrict__ wch2,
    const float* __restrict__ wch3,
    float* __restrict__ d0, unsigned short* __restrict__ c1t,
    unsigned short* __restrict__ d1, unsigned short* __restrict__ d2t)
{
    __shared__ float w2s[64][64];                            // [co][ci]
    __shared__ float wc1[32][64], wc2[32][64], wc3[32][64];  // [co2][ci]
    __shared__ float b2s[64];
    __shared__ float c0buf[64][65];                          // [pixel][ci], padded

    int tid = threadIdx.x;
    for (int i = tid; i < 4096; i += 256) w2s[i >> 6][i & 63] = w2[i];
    for (int i = tid; i < 2048; i += 256){
        int co2 = i >> 6, ci = i & 63;
        wc1[co2][ci] = wch1[i];
        wc2[co2][ci] = wch2[i];
        wc3[co2][ci] = wch3[i];
    }
    if (tid < 64) b2s[tid] = b2[tid];
    float a2 = a2p[0];
    __syncthreads();

    int pl = tid & 63, grp = tid >> 6;
    int P = blockIdx.x * 64 + pl;
    int b = P / NPIX, p = P % NPIX;

    for (int mod = 0; mod < 2; ++mod){
        const float* tp = t + (size_t)(mod*2 + b) * CC * NPIX + p;
        float acc[16];
        #pragma unroll
        for (int i = 0; i < 16; ++i) acc[i] = 0.f;
        for (int ci = 0; ci < 64; ++ci){
            float x = tp[ci * NPIX];
            #pragma unroll
            for (int i = 0; i < 16; ++i) acc[i] = fmaf(x, w2s[grp*16 + i][ci], acc[i]);
        }
        float c0v[16];
        #pragma unroll
        for (int i = 0; i < 16; ++i){
            float v = acc[i] + b2s[grp*16 + i];
            c0v[i] = (v >= 0.f) ? v : a2 * v;
        }
        __syncthreads();                       // protect c0buf from previous pass readers
        #pragma unroll
        for (int i = 0; i < 16; ++i) c0buf[pl][grp*16 + i] = c0v[i];
        __syncthreads();

        if (mod == 0){
            float ca[8];
            #pragma unroll
            for (int j = 0; j < 8; ++j) ca[j] = 0.f;
            for (int ci = 0; ci < 64; ++ci){
                float xc = c0buf[pl][ci];
                #pragma unroll
                for (int j = 0; j < 8; ++j) ca[j] = fmaf(xc, wc1[grp*8 + j][ci], ca[j]);
            }
            #pragma unroll
            for (int j = 0; j < 8; ++j)
                c1t[((size_t)b * CH + grp*8 + j) * NPIX + p] = f2b(ca[j]);
        } else {
            #pragma unroll
            for (int i = 0; i < 16; ++i)
                d0[((size_t)b * CC + grp*16 + i) * NPIX + p] = c0v[i];
            float ca[8], cb[8];
            #pragma unroll
            for (int j = 0; j < 8; ++j){ ca[j] = 0.f; cb[j] = 0.f; }
            for (int ci = 0; ci < 64; ++ci){
                float xc = c0buf[pl][ci];
                #pragma unroll
                for (int j = 0; j < 8; ++j){
                    ca[j] = fmaf(xc, wc2[grp*8 + j][ci], ca[j]);
                    cb[j] = fmaf(xc, wc3[grp*8 + j][ci], cb[j]);
                }
            }
            #pragma unroll
            for (int j = 0; j < 8; ++j){
                d1 [((size_t)b * NPIX + p) * CH + grp*8 + j] = f2b(ca[j]);
                d2t[((size_t)b * NPIX + p) * CH + grp*8 + j] = f2b(cb[j]);
            }
        }
    }
}

// ---------- attention helpers --------------------------------------------
// LDS tile layouts (per buffer, 8 KB):
//   K: [64 rows][64 B], 16B-chunk swizzle: LDS(r, c) = G(r, c ^ (r&3))
//   V: [32 rows][128 B], 16B-chunk swizzle: LDS(d, c) = G(d, c ^ (d&7))
// global_load_lds writes linearly (wave base + lane*16); the swizzle is
// applied on the per-lane GLOBAL source address (rule #21), and the same
// XOR on the ds_read side. V unswizzled would be a 16-way bank conflict.

static __device__ __forceinline__ void stage_kv(
    const char* kTile, const char* vTile, char* klds, char* vlds,
    int tid, int wid)
{
    // K tile is 4096 contiguous bytes (row stride 64B). LDS chunk = tid.
    int rK = tid >> 2;
    int cK = (tid & 3) ^ (rK & 3);
    __builtin_amdgcn_global_load_lds(
        (const __attribute__((address_space(1))) void*)(kTile + rK*64 + cK*16),
        (__attribute__((address_space(3))) void*)(klds + wid*1024), 16, 0, 0);
    // V tile: 32 rows x 128B, global row stride 18432B. LDS chunk = tid.
    int dV = tid >> 3;
    int cV = (tid & 7) ^ (dV & 7);
    __builtin_amdgcn_global_load_lds(
        (const __attribute__((address_space(1))) void*)(vTile + dV*18432 + cV*16),
        (__attribute__((address_space(3))) void*)(vlds + wid*1024), 16, 0, 0);
}

static __device__ __forceinline__ void read_frags(
    const char* klds, const char* vlds, int l16, int lg,
    FragU kf[4], FragU vf[4])
{
    int w16 = (lg & 1) * 8;
    int cK0 = lg >> 1;
    #pragma unroll
    for (int j = 0; j < 4; ++j){
        int r = j*16 + l16;
        int rx = r & 3;
        const char* rowp = klds + r*64 + w16;
        kf[j].q[0] = *(const u2ma*)(rowp + ((cK0       ^ rx) * 16));
        kf[j].q[1] = *(const u2ma*)(rowp + (((cK0 + 2) ^ rx) * 16));
    }
    #pragma unroll
    for (int w = 0; w < 2; ++w)
        #pragma unroll
        for (int jt = 0; jt < 2; ++jt){
            int d = jt*16 + l16;
            int dx = d & 7;
            const char* rowp = vlds + d*128 + w16;
            int c0 = w*4 + (lg >> 1);
            vf[w*2 + jt].q[0] = *(const u2ma*)(rowp + (((c0    ) ^ dx) * 16));
            vf[w*2 + jt].q[1] = *(const u2ma*)(rowp + (((c0 + 2) ^ dx) * 16));
        }
}

static __device__ __forceinline__ void compute_tile(
    const FragU& qf, FragU kf[4], FragU vf[4],
    f32x4& o0, f32x4& o1, float& m, float& lsum)
{
    // S^T tile j: rows k = kb+j*16+lg*4+i, col q = l16
    f32x4 s[4];
    #pragma unroll
    for (int j = 0; j < 4; ++j){
        f32x4 z = {0.f,0.f,0.f,0.f};
        s[j] = __builtin_amdgcn_mfma_f32_16x16x32_bf16(kf[j].v, qf.v, z, 0, 0, 0);
    }
    // online softmax over this lane's q-column
    float pm = fmaxf(fmaxf(hmax4(s[0]), hmax4(s[1])),
                     fmaxf(hmax4(s[2]), hmax4(s[3])));
    pm = fmaxf(pm, __shfl_xor(pm, 16));
    pm = fmaxf(pm, __shfl_xor(pm, 32));
    float mn = fmaxf(m, pm);
    float al = __expf(m - mn);
    m = mn;
    #pragma unroll
    for (int j = 0; j < 4; ++j)
        #pragma unroll
        for (int i = 0; i < 4; ++i)
            s[j][i] = __expf(s[j][i] - m);     // exp in place
    float ps = (hadd4(s[0]) + hadd4(s[1])) + (hadd4(s[2]) + hadd4(s[3]));
    ps += __shfl_xor(ps, 16);
    ps += __shfl_xor(ps, 32);
    lsum = lsum * al + ps;
    o0 *= al;
    o1 *= al;
    // pack P^T B-frags in-register
    FragU p0, p1;
    p0.w[0] = pk_bf16(s[0][0], s[0][1]);
    p0.w[1] = pk_bf16(s[0][2], s[0][3]);
    p0.w[2] = pk_bf16(s[1][0], s[1][1]);
    p0.w[3] = pk_bf16(s[1][2], s[1][3]);
    p1.w[0] = pk_bf16(s[2][0], s[2][1]);
    p1.w[1] = pk_bf16(s[2][2], s[2][3]);
    p1.w[2] = pk_bf16(s[3][0], s[3][1]);
    p1.w[3] = pk_bf16(s[3][2], s[3][3]);
    // O^T += V^T P^T
    o0 = __builtin_amdgcn_mfma_f32_16x16x32_bf16(vf[0].v, p0.v, o0, 0, 0, 0);
    o1 = __builtin_amdgcn_mfma_f32_16x16x32_bf16(vf[1].v, p0.v, o1, 0, 0, 0);
    o0 = __builtin_amdgcn_mfma_f32_16x16x32_bf16(vf[2].v, p1.v, o0, 0, 0, 0);
    o1 = __builtin_amdgcn_mfma_f32_16x16x32_bf16(vf[3].v, p1.v, o1, 0, 0, 0);
}

// ---------- kernel 3: flash attention, K-split, LDS-staged K/V (DMA) --------
// grid (144, B, NSPLIT); block 256 = 4 waves; wave = 16 query rows; KBLK = 64
// All 4 waves share one K/V tile per iteration (4x load dedup); double-buffered
// LDS; global_load_lds DMA for tile t+1 issues before compute of tile t.
__global__ __launch_bounds__(256, 4) void k_attn(
    const unsigned short* __restrict__ d1, const unsigned short* __restrict__ d2t,
    const unsigned short* __restrict__ c1t, float* __restrict__ Opart,
    float* __restrict__ mpart, float* __restrict__ lpart)
{
    __shared__ char smem[2][8192];        // [buf][K 4KB | V 4KB]
    int tid  = threadIdx.x;
    int b    = blockIdx.y;
    int sp   = blockIdx.z;
    int wid  = tid >> 6;
    int lane = tid & 63;
    int l16  = lane & 15;
    int lg   = lane >> 4;                 // 0..3
    int q0   = (blockIdx.x * 4 + wid) * 16;

    const char* kBase = (const char*)(d2t + (size_t)b * NPIX * CH);
    const char* vBase = (const char*)(c1t + (size_t)b * CH * NPIX);
    int t0 = sp * KPT;

    FragU qf;   // B-frag of Q^T == per-lane rows of Q
    {
        const unsigned short* qp = d1 + ((size_t)b * NPIX + q0 + l16) * CH + lg * 4;
        qf.q[0] = *(const u2ma*)qp;
        qf.q[1] = *(const u2ma*)(qp + 16);
    }

    f32x4 o0 = {0.f,0.f,0.f,0.f}, o1 = {0.f,0.f,0.f,0.f};   // O^T d-tiles 0,1
    float m = -1e30f, lsum = 0.f;

    stage_kv(kBase + (size_t)t0 * 4096, vBase + (size_t)t0 * 128,
             smem[0], smem[0] + 4096, tid, wid);
    __syncthreads();                       // compiler drains vmcnt before barrier

    int cur = 0;
    #pragma unroll 1
    for (int it = 0; it < KPT; ++it){
        if (it + 1 < KPT)
            stage_kv(kBase + (size_t)(t0 + it + 1) * 4096,
                     vBase + (size_t)(t0 + it + 1) * 128,
                     smem[cur ^ 1], smem[cur ^ 1] + 4096, tid, wid);
        FragU kf[4], vf[4];
        read_frags(smem[cur], smem[cur] + 4096, l16, lg, kf, vf);
        compute_tile(qf, kf, vf, o0, o1, m, lsum);
        __syncthreads();                   // next tile's DMA + this tile's reads done
        cur ^= 1;
    }

    // --- write unnormalized partials: lane holds q = q0+l16, d = jt*16+lg*4+i ---
    size_t prow = (size_t)(sp * BB + b) * NPIX + q0 + l16;
    float4 st0 = {o0[0], o0[1], o0[2], o0[3]};
    float4 st1 = {o1[0], o1[1], o1[2], o1[3]};
    *(f4ma*)(Opart + prow * CH + lg*4)      = st0;
    *(f4ma*)(Opart + prow * CH + 16 + lg*4) = st1;
    if (lg == 0){
        mpart[prow] = m;
        lpart[prow] = lsum;
    }
}

// ---------- kernel 4: combine K-split partials + 1x1 conv (32->64) + residual --
// block 256 = 64 pixels x 4 cout-groups; grid 288
__global__ __launch_bounds__(256) void k_final(
    const float* __restrict__ Opart, const float* __restrict__ mpart,
    const float* __restrict__ lpart, const float* __restrict__ wch4,
    const float* __restrict__ d0, float* __restrict__ out)
{
    __shared__ float w4s[64][32];   // [co][d]
    __shared__ float ob[64][33];    // combined O per pixel, padded
    int tid = threadIdx.x;
    for (int i = tid; i < 2048; i += 256) w4s[i >> 5][i & 31] = wch4[i];
    int pl = tid & 63, grp = tid >> 6;
    int P = blockIdx.x * 64 + pl;
    int b = P / NPIX, p = P % NPIX;

    // combine: thread (pl,grp) merges d = grp*8 .. grp*8+7
    float mv[NSPLIT];
    float M = -1e30f;
    #pragma unroll
    for (int s = 0; s < NSPLIT; ++s){
        mv[s] = mpart[(size_t)(s * BB + b) * NPIX + p];
        M = fmaxf(M, mv[s]);
    }
    float L = 0.f, acc8[8];
    #pragma unroll
    for (int j = 0; j < 8; ++j) acc8[j] = 0.f;
    #pragma unroll
    for (int s = 0; s < NSPLIT; ++s){
        float w = __expf(mv[s] - M);
        L += w * lpart[(size_t)(s * BB + b) * NPIX + p];
        const float* op = Opart + ((size_t)(s * BB + b) * NPIX + p) * CH + grp*8;
        #pragma unroll
        for (int j = 0; j < 8; ++j) acc8[j] = fmaf(w, op[j], acc8[j]);
    }
    float invL = 1.f / L;
    #pragma unroll
    for (int j = 0; j < 8; ++j) ob[pl][grp*8 + j] = acc8[j] * invL;
    __syncthreads();

    float acc[16];
    #pragma unroll
    for (int i = 0; i < 16; ++i) acc[i] = 0.f;
    #pragma unroll
    for (int d = 0; d < 32; ++d){
        float x = ob[pl][d];
        #pragma unroll
        for (int i = 0; i < 16; ++i) acc[i] = fmaf(x, w4s[grp*16 + i][d], acc[i]);
    }
    #pragma unroll
    for (int i = 0; i < 16; ++i){
        size_t idx = ((size_t)b * CC + grp*16 + i) * NPIX + p;
        out[idx] = acc[i] + d0[idx];
    }
}

// ---------- launch ----------
extern "C" void kernel_launch(void* const* d_in, const int* in_sizes, int n_in,
                              void* d_out, int out_size, void* d_ws, size_t ws_size,
                              hipStream_t stream) {
    const float* rgb  = (const float*)d_in[0];
    const float* dep  = (const float*)d_in[1];
    const float* w1   = (const float*)d_in[2];
    const float* b1   = (const float*)d_in[3];
    const float* a1   = (const float*)d_in[4];
    const float* w2   = (const float*)d_in[5];
    const float* b2   = (const float*)d_in[6];
    const float* a2   = (const float*)d_in[7];
    const float* wch1 = (const float*)d_in[8];
    const float* wch2 = (const float*)d_in[9];
    const float* wch3 = (const float*)d_in[10];
    const float* wch4 = (const float*)d_in[11];

    char* ws = (char*)d_ws;
    float* t             = (float*)(ws);                          //  9,437,184 B
    float* d0            = (float*)(ws + 9437184);                //  4,718,592 B
    unsigned short* c1t  = (unsigned short*)(ws + 14155776);      //  1,179,648 B
    unsigned short* d1   = (unsigned short*)(ws + 15335424);      //  1,179,648 B
    unsigned short* d2t  = (unsigned short*)(ws + 16515072);      //  1,179,648 B
    float* Opart         = (float*)(ws + 17694720);               // 14,155,776 B
    float* mpart         = (float*)(ws + 31850496);               //    442,368 B
    float* lpart         = (float*)(ws + 32292864);               //    442,368 B
    // total ws use: 32,735,232 B

    k_trunk1<<<dim3(6,6,16), 256, 0, stream>>>(rgb, dep, w1, b1, a1, t);
    k_trunk2<<<288, 256, 0, stream>>>(t, w2, b2, a2, wch1, wch2, wch3, d0, c1t, d1, d2t);
    k_attn  <<<dim3(NKV, BB, NSPLIT), 256, 0, stream>>>(d1, d2t, c1t, Opart, mpart, lpart);
    k_final <<<288, 256, 0, stream>>>(Opart, mpart, lpart, wch4, d0, (float*)d_out);
}